// Round 3
// baseline (322.706 us; speedup 1.0000x reference)
//
#include <hip/hip_runtime.h>
#include <math.h>

// NSVQ: N=131072 rows, D=64, K=1024 codes (fp32).
// out (flat f32): [0,N*D) quantized; [N*D] perplexity; [N*D+1,+K) counts.
// ws: [0,4KB) cn f32[K]; [4KB,8KB) counts int[K]; [8KB,+N*4) best int[N].

#define NSVQ_D 64
#define ABN 128   // rows per argmin block
#define ABK 128   // codes per chunk
#define EPS_FLAG 0.01f

typedef __attribute__((ext_vector_type(8))) short short8;
typedef __attribute__((ext_vector_type(4))) float f32x4;

__device__ __forceinline__ ushort bftrunc(float f) {
  return (ushort)(__float_as_uint(f) >> 16);
}
__device__ __forceinline__ float bf2f(ushort h) {
  return __uint_as_float(((uint)h) << 16);
}

// ---------------- codebook norms ----------------
__global__ void nsvq_cnorm_kernel(const float* __restrict__ cb,
                                  float* __restrict__ cn, int K) {
  int k = blockIdx.x * blockDim.x + threadIdx.x;
  if (k >= K) return;
  const float4* p = (const float4*)(cb + (long)k * NSVQ_D);
  float s = 0.f;
#pragma unroll
  for (int i = 0; i < NSVQ_D / 4; ++i) {
    float4 v = p[i];
    s += v.x * v.x + v.y * v.y + v.z * v.z + v.w * v.w;
  }
  cn[k] = s;
}

// ---------------- MFMA argmin (bf16 3-term split, top-2 tracked) ----------------
__global__ __launch_bounds__(256, 2)
void nsvq_argmin_mfma(const float* __restrict__ x,
                      const float* __restrict__ cb,
                      const float* __restrict__ cn,
                      int* __restrict__ best) {
  // double-buffered C chunk: [buf][hi/lo][128 rows * 64 bf16], XOR-swizzled
  __shared__ ushort CS[2][2][ABK * 64];  // 64 KB
  __shared__ float MS1[4][64], MS2[4][64];  // per-wave per-row top-2 (cross-wave merge)
  __shared__ int MI1[4][64];
  const int tid = threadIdx.x;
  const int lane = tid & 63;
  const int wid = tid >> 6;           // 0..3
  const int cw = wid & 1;             // col-wave (0..1): codes (k mod 128) in [cw*64, cw*64+64)
  const int wrow = (wid >> 1) * 64;   // row-wave base (0 or 64)
  const int l15 = lane & 15;
  const int lg = lane >> 4;           // 0..3
  const long brow = (long)blockIdx.x * ABN;

  // ---- A fragments (X rows) from global, bf16 hi/lo, register-resident ----
  short8 ah[4][2], al[4][2];
#pragma unroll
  for (int rt = 0; rt < 4; ++rt) {
#pragma unroll
    for (int kk = 0; kk < 2; ++kk) {
      const float* xr = x + (brow + wrow + rt * 16 + l15) * NSVQ_D + kk * 32 + lg * 8;
      float4 v0 = *(const float4*)xr;
      float4 v1 = *(const float4*)(xr + 4);
      float f[8] = {v0.x, v0.y, v0.z, v0.w, v1.x, v1.y, v1.z, v1.w};
      short8 h, lo;
#pragma unroll
      for (int j = 0; j < 8; ++j) {
        ushort hb = bftrunc(f[j]);
        h[j] = (short)hb;
        lo[j] = (short)bftrunc(f[j] - bf2f(hb));
      }
      ah[rt][kk] = h;
      al[rt][kk] = lo;
    }
  }

  // ---- staging helpers (fp32 -> bf16 hi/lo into swizzled LDS) ----
  float4 sr[8];
  auto stage_load = [&](int c) {
#pragma unroll
    for (int it = 0; it < 8; ++it) {
      int f = tid + it * 256;  // float4 index within chunk (2048)
      sr[it] = *(const float4*)(cb + ((long)c * ABK + (f >> 4)) * NSVQ_D + (f & 15) * 4);
    }
  };
  auto stage_write = [&](int b) {
#pragma unroll
    for (int it = 0; it < 8; ++it) {
      int f = tid + it * 256;
      int row = f >> 4, c4 = f & 15;
      uint u0 = __float_as_uint(sr[it].x), u1 = __float_as_uint(sr[it].y);
      uint u2 = __float_as_uint(sr[it].z), u3 = __float_as_uint(sr[it].w);
      uint2 hp, lp;
      hp.x = (u0 >> 16) | (u1 & 0xFFFF0000u);
      hp.y = (u2 >> 16) | (u3 & 0xFFFF0000u);
      float l0 = sr[it].x - bf2f((ushort)(u0 >> 16));
      float l1 = sr[it].y - bf2f((ushort)(u1 >> 16));
      float l2 = sr[it].z - bf2f((ushort)(u2 >> 16));
      float l3 = sr[it].w - bf2f((ushort)(u3 >> 16));
      lp.x = (__float_as_uint(l0) >> 16) | (__float_as_uint(l1) & 0xFFFF0000u);
      lp.y = (__float_as_uint(l2) >> 16) | (__float_as_uint(l3) & 0xFFFF0000u);
      int byteoff = row * 128 + (((c4 >> 1) ^ (row & 7)) << 4) + ((c4 & 1) << 3);
      *(uint2*)((char*)&CS[b][0][0] + byteoff) = hp;
      *(uint2*)((char*)&CS[b][1][0] + byteoff) = lp;
    }
  };

  float s1[16], s2[16];
  int i1[16];
#pragma unroll
  for (int i = 0; i < 16; ++i) { s1[i] = 3.4e38f; s2[i] = 3.4e38f; i1[i] = 0; }

  stage_load(0);
  stage_write(0);
  stage_load(1);
  __syncthreads();

  const int nchunk = 1024 / ABK;  // 8
  for (int c = 0; c < nchunk; ++c) {
    char* chb = (char*)&CS[c & 1][0][0];
    char* clb = (char*)&CS[c & 1][1][0];
#pragma unroll
    for (int ct = 0; ct < 4; ++ct) {
      int crow = cw * 64 + ct * 16 + l15;
      short8 bh[2], bl[2];
#pragma unroll
      for (int kk = 0; kk < 2; ++kk) {
        int byteoff = crow * 128 + ((((kk << 2) + lg) ^ (crow & 7)) << 4);
        bh[kk] = *(short8*)(chb + byteoff);
        bl[kk] = *(short8*)(clb + byteoff);
      }
      int kidx = c * ABK + crow;
      float cnv = cn[kidx];
#pragma unroll
      for (int rt = 0; rt < 4; ++rt) {
        f32x4 acc = {0.f, 0.f, 0.f, 0.f};
        acc = __builtin_amdgcn_mfma_f32_16x16x32_bf16(ah[rt][0], bh[0], acc, 0, 0, 0);
        acc = __builtin_amdgcn_mfma_f32_16x16x32_bf16(ah[rt][1], bh[1], acc, 0, 0, 0);
        acc = __builtin_amdgcn_mfma_f32_16x16x32_bf16(al[rt][0], bh[0], acc, 0, 0, 0);
        acc = __builtin_amdgcn_mfma_f32_16x16x32_bf16(al[rt][1], bh[1], acc, 0, 0, 0);
        acc = __builtin_amdgcn_mfma_f32_16x16x32_bf16(ah[rt][0], bl[0], acc, 0, 0, 0);
        acc = __builtin_amdgcn_mfma_f32_16x16x32_bf16(ah[rt][1], bl[1], acc, 0, 0, 0);
#pragma unroll
        for (int j = 0; j < 4; ++j) {
          float s = fmaf(-2.f, acc[j], cnv);
          int slot = rt * 4 + j;
          bool bt = s < s1[slot];
          s2[slot] = fminf(s2[slot], fmaxf(s1[slot], s));
          if (bt) { s1[slot] = s; i1[slot] = kidx; }
        }
      }
    }
    if (c < nchunk - 1) {
      stage_write((c + 1) & 1);
      if (c < nchunk - 2) stage_load(c + 2);
    }
    __syncthreads();
  }

  // ---- cross-lane top-2 merge within 16-lane col groups; deposit per-wave result ----
#pragma unroll
  for (int rt = 0; rt < 4; ++rt) {
#pragma unroll
    for (int j = 0; j < 4; ++j) {
      int slot = rt * 4 + j;
      float a1 = s1[slot], a2 = s2[slot];
      int ai = i1[slot];
#pragma unroll
      for (int off = 1; off < 16; off <<= 1) {
        float t1 = __shfl_xor(a1, off);
        int ti = __shfl_xor(ai, off);
        float t2 = __shfl_xor(a2, off);
        bool tb = (t1 < a1) || (t1 == a1 && ti < ai);
        float n2 = tb ? fminf(a1, t2) : fminf(a2, t1);
        if (tb) { a1 = t1; ai = ti; }
        a2 = n2;
      }
      if (l15 == 0) {
        int lr = rt * 16 + lg * 4 + j;  // local row 0..63 within this wave's row half
        MS1[wid][lr] = a1;
        MS2[wid][lr] = a2;
        MI1[wid][lr] = ai;
      }
    }
  }
  __syncthreads();

  // ---- cross-wave merge: cw==0 wave merges its half with partner (wid|1) ----
  if (cw == 0) {
    float a1 = MS1[wid][lane], a2 = MS2[wid][lane];
    int ai = MI1[wid][lane];
    float t1 = MS1[wid + 1][lane], t2 = MS2[wid + 1][lane];
    int ti = MI1[wid + 1][lane];
    bool tb = (t1 < a1) || (t1 == a1 && ti < ai);
    float n2 = tb ? fminf(a1, t2) : fminf(a2, t1);
    if (tb) { a1 = t1; ai = ti; }
    a2 = n2;
    long row = brow + wrow + lane;
    best[row] = (a2 - a1 < EPS_FLAG) ? (-ai - 1) : ai;  // negative = needs exact recheck
  }
}

// ---------------- cleanup: exact recheck of flagged rows + counts histogram ----------------
__global__ __launch_bounds__(256)
void nsvq_cleanup(const float* __restrict__ x,
                  const float* __restrict__ cb,
                  const float* __restrict__ cn,
                  int* __restrict__ best,
                  int* __restrict__ counts, int N, int K) {
  __shared__ int hist[1024];
  for (int i = threadIdx.x; i < K; i += 256) hist[i] = 0;
  __syncthreads();
  const int lane = threadIdx.x & 63;
  const int wave = (blockIdx.x << 2) | (threadIdx.x >> 6);
  const long r0 = (long)wave * 64;
  for (long row = r0; row < r0 + 64; ++row) {
    int b = best[row];
    if (b >= 0) {
      if (lane == 0) atomicAdd(&hist[b], 1);
      continue;
    }
    // exact fp32 rescan over all K codes: lane handles codes [lane*16, lane*16+16)
    float4 xr[16];
#pragma unroll
    for (int q = 0; q < 16; ++q) xr[q] = *(const float4*)(x + row * NSVQ_D + q * 4);
    float bs = 3.4e38f;
    int bk = 0;
    for (int m = 0; m < 16; ++m) {
      int k = lane * 16 + m;
      const float4* cp = (const float4*)(cb + (long)k * NSVQ_D);
      float dot = 0.f;
#pragma unroll
      for (int q = 0; q < 16; ++q) {
        float4 cv = cp[q];
        dot = fmaf(xr[q].x, cv.x, dot);
        dot = fmaf(xr[q].y, cv.y, dot);
        dot = fmaf(xr[q].z, cv.z, dot);
        dot = fmaf(xr[q].w, cv.w, dot);
      }
      float s = fmaf(-2.f, dot, cn[k]);
      if (s < bs) { bs = s; bk = k; }
    }
#pragma unroll
    for (int off = 1; off < 64; off <<= 1) {
      float s2v = __shfl_xor(bs, off);
      int k2 = __shfl_xor(bk, off);
      if (s2v < bs || (s2v == bs && k2 < bk)) { bs = s2v; bk = k2; }
    }
    if (lane == 0) {
      best[row] = bk;
      atomicAdd(&hist[bk], 1);
    }
  }
  __syncthreads();
  for (int i = threadIdx.x; i < K; i += 256) {
    int v = hist[i];
    if (v) atomicAdd(&counts[i], v);
  }
}

// ---------------- epilogue: noise-substitution quantization ----------------
__global__ __launch_bounds__(256)
void nsvq_epilogue_kernel(const float* __restrict__ x,
                          const float* __restrict__ cb,
                          const float* __restrict__ rv,
                          const int* __restrict__ best,
                          float* __restrict__ out) {
  const int tid = threadIdx.x;
  const long row = (long)blockIdx.x * 16 + (tid >> 4);
  const int l = tid & 15;
  const int k = best[row];

  float4 xv = ((const float4*)(x + row * NSVQ_D))[l];
  float4 cv = ((const float4*)(cb + (long)k * NSVQ_D))[l];
  float4 rr = ((const float4*)(rv + row * NSVQ_D))[l];

  float dx = xv.x - cv.x, dy = xv.y - cv.y, dz = xv.z - cv.z, dw = xv.w - cv.w;
  float dres = dx * dx + dy * dy + dz * dz + dw * dw;
  float drnd = rr.x * rr.x + rr.y * rr.y + rr.z * rr.z + rr.w * rr.w;
#pragma unroll
  for (int off = 1; off < 16; off <<= 1) {
    dres += __shfl_xor(dres, off, 64);
    drnd += __shfl_xor(drnd, off, 64);
  }
  float scale = sqrtf(dres) / (sqrtf(drnd) + 1e-12f);

  float4 o;
  o.x = xv.x + scale * rr.x;
  o.y = xv.y + scale * rr.y;
  o.z = xv.z + scale * rr.z;
  o.w = xv.w + scale * rr.w;
  ((float4*)(out + row * NSVQ_D))[l] = o;
}

// ---------------- perplexity + counts output ----------------
__global__ void nsvq_perp_kernel(const int* __restrict__ counts,
                                 float* __restrict__ out_tail,  // [0]=perp, [1..K]=counts
                                 float invN, int K) {
  int t = threadIdx.x;
  float v = 0.f;
  if (t < K) {
    int c = counts[t];
    out_tail[1 + t] = (float)c;
    float p = (float)c * invN;
    v = p * logf(p + 1e-12f);
  }
#pragma unroll
  for (int off = 1; off < 64; off <<= 1) v += __shfl_xor(v, off, 64);
  __shared__ float red[16];
  int wid = t >> 6;
  if ((t & 63) == 0) red[wid] = v;
  __syncthreads();
  if (t == 0) {
    float s = 0.f;
    int nw = (blockDim.x + 63) / 64;
    for (int w = 0; w < nw; ++w) s += red[w];
    out_tail[0] = expf(-s);
  }
}

extern "C" void kernel_launch(void* const* d_in, const int* in_sizes, int n_in,
                              void* d_out, int out_size, void* d_ws, size_t ws_size,
                              hipStream_t stream) {
  const float* x  = (const float*)d_in[0];
  const float* cb = (const float*)d_in[1];
  const float* rv = (const float*)d_in[2];
  float* out = (float*)d_out;

  const int D = NSVQ_D;
  const int N = in_sizes[0] / D;  // 131072
  const int K = in_sizes[1] / D;  // 1024

  float* cn   = (float*)d_ws;
  int* counts = (int*)((char*)d_ws + 4096);
  int* best   = (int*)((char*)d_ws + 8192);

  hipMemsetAsync(counts, 0, (size_t)K * sizeof(int), stream);
  nsvq_cnorm_kernel<<<(K + 255) / 256, 256, 0, stream>>>(cb, cn, K);
  nsvq_argmin_mfma<<<N / ABN, 256, 0, stream>>>(x, cb, cn, best);
  nsvq_cleanup<<<N / (64 * 4), 256, 0, stream>>>(x, cb, cn, best, counts, N, K);
  nsvq_epilogue_kernel<<<N / 16, 256, 0, stream>>>(x, cb, rv, best, out);
  nsvq_perp_kernel<<<1, 1024, 0, stream>>>(counts, out + (size_t)N * D, 1.0f / (float)N, K);
}

// Round 4
// 303.143 us; speedup vs baseline: 1.0645x; 1.0645x over previous
//
#include <hip/hip_runtime.h>
#include <math.h>

// NSVQ: N=131072 rows, D=64, K=1024 codes (fp32).
// out (flat f32): [0,N*D) quantized; [N*D] perplexity; [N*D+1,+K) counts.
// ws layout:
//   [0,4096)        cn256  f32[K]      (||c||^2 + 256)
//   [4096,8192)     counts int[K]
//   [8192,270336)   best   ushort[N]   (bit15 = needs exact recheck)
//   [270336,401408) cbh    ushort[K*64] bf16 hi, swizzled 16B blocks
//   [401408,532480) cbl    ushort[K*64] bf16 lo, swizzled 16B blocks

#define NSVQ_D 64
#define ABN 512          // rows per argmin block
#define EPS_FLAG 0.15f   // covers 2*(0.0625 packing) + bf16-split error

typedef __attribute__((ext_vector_type(8))) short short8;
typedef __attribute__((ext_vector_type(4))) float f32x4;

__device__ __forceinline__ ushort bftrunc(float f) {
  return (ushort)(__float_as_uint(f) >> 16);
}
__device__ __forceinline__ float bf2f(ushort h) {
  return __uint_as_float(((uint)h) << 16);
}

// ---------------- prep: codebook norms + bf16 hi/lo split (swizzled) + zero counts ----------------
__global__ __launch_bounds__(256)
void nsvq_prep(const float* __restrict__ cb,
               ushort* __restrict__ cbh, ushort* __restrict__ cbl,
               float* __restrict__ cn, int* __restrict__ counts, int K) {
  if (blockIdx.x == 0) ((int4*)counts)[threadIdx.x] = make_int4(0, 0, 0, 0);
  int r = blockIdx.x * 256 + threadIdx.x;  // one code per thread
  if (r >= K) return;
  const float* row = cb + (long)r * NSVQ_D;
  float nrm = 0.f;
#pragma unroll
  for (int j = 0; j < 8; ++j) {            // dim block j = dims 8j..8j+7
    float4 v0 = *(const float4*)(row + j * 8);
    float4 v1 = *(const float4*)(row + j * 8 + 4);
    float f[8] = {v0.x, v0.y, v0.z, v0.w, v1.x, v1.y, v1.z, v1.w};
    ushort h[8], l[8];
#pragma unroll
    for (int e = 0; e < 8; ++e) {
      nrm = fmaf(f[e], f[e], nrm);
      ushort hb = bftrunc(f[e]);
      h[e] = hb;
      l[e] = bftrunc(f[e] - bf2f(hb));
    }
    int blk = r * 8 + (j ^ (r & 7));       // swizzled 16B block index
    *(uint4*)(cbh + blk * 8) = *(uint4*)h;
    *(uint4*)(cbl + blk * 8) = *(uint4*)l;
  }
  cn[r] = nrm + 256.f;                     // offset keeps scores positive for bit-packing
}

// ---------------- MFMA argmin: 512 rows/block, packed-u32 top-2 ----------------
__global__ __launch_bounds__(512, 2)
void nsvq_argmin_mfma(const float* __restrict__ x,
                      const ushort* __restrict__ cbh,
                      const ushort* __restrict__ cbl,
                      const float* __restrict__ cn,
                      ushort* __restrict__ best) {
  __shared__ ushort CS[2][2][128 * 64];    // [buf][hi/lo][code*64], 64 KB, swizzled
  const int tid = threadIdx.x;
  const int lane = tid & 63;
  const int wid = tid >> 6;                // 0..7, each wave owns 64 rows
  const int l15 = lane & 15;
  const int lg = lane >> 4;                // 0..3
  const long brow = (long)blockIdx.x * ABN;
  const int wrow = wid * 64;

  // ---- A fragments (X rows), bf16 hi/lo, register-resident for whole K loop ----
  short8 ah[4][2], al[4][2];
#pragma unroll
  for (int rt = 0; rt < 4; ++rt) {
#pragma unroll
    for (int kk = 0; kk < 2; ++kk) {
      const float* xr = x + (brow + wrow + rt * 16 + l15) * NSVQ_D + kk * 32 + lg * 8;
      float4 v0 = *(const float4*)xr;
      float4 v1 = *(const float4*)(xr + 4);
      float f[8] = {v0.x, v0.y, v0.z, v0.w, v1.x, v1.y, v1.z, v1.w};
      short8 h, lo;
#pragma unroll
      for (int j = 0; j < 8; ++j) {
        ushort hb = bftrunc(f[j]);
        h[j] = (short)hb;
        lo[j] = (short)bftrunc(f[j] - bf2f(hb));
      }
      ah[rt][kk] = h;
      al[rt][kk] = lo;
    }
  }

  // ---- linear chunk staging (pre-swizzled in ws): 32 KB per chunk ----
  uint4 st[4];
  auto stage_load = [&](int c) {
    const uint4* ph = (const uint4*)cbh + c * 1024;
    const uint4* pl = (const uint4*)cbl + c * 1024;
    st[0] = ph[tid];
    st[1] = ph[tid + 512];
    st[2] = pl[tid];
    st[3] = pl[tid + 512];
  };
  auto stage_write = [&](int b) {
    uint4* dh = (uint4*)&CS[b][0][0];
    uint4* dl = (uint4*)&CS[b][1][0];
    dh[tid] = st[0];
    dh[tid + 512] = st[1];
    dl[tid] = st[2];
    dl[tid + 512] = st[3];
  };

  uint u1[16], u2[16];
#pragma unroll
  for (int i = 0; i < 16; ++i) { u1[i] = 0xFFFFFFFFu; u2[i] = 0xFFFFFFFFu; }

  stage_load(0);
  stage_write(0);
  stage_load(1);
  __syncthreads();

  for (int c = 0; c < 8; ++c) {            // 8 chunks x 128 codes
    char* chb = (char*)&CS[c & 1][0][0];
    char* clb = (char*)&CS[c & 1][1][0];
#pragma unroll
    for (int ct = 0; ct < 8; ++ct) {
      int crow = ct * 16 + l15;            // code within chunk
      short8 bh[2], bl[2];
#pragma unroll
      for (int kk = 0; kk < 2; ++kk) {
        int byteoff = crow * 128 + ((((kk << 2) + lg) ^ (crow & 7)) << 4);
        bh[kk] = *(short8*)(chb + byteoff);
        bl[kk] = *(short8*)(clb + byteoff);
      }
      uint kidx = (uint)(c * 128 + crow);
      float cnv = cn[kidx];
#pragma unroll
      for (int rt = 0; rt < 4; ++rt) {
        f32x4 acc = {0.f, 0.f, 0.f, 0.f};
        acc = __builtin_amdgcn_mfma_f32_16x16x32_bf16(ah[rt][0], bh[0], acc, 0, 0, 0);
        acc = __builtin_amdgcn_mfma_f32_16x16x32_bf16(ah[rt][1], bh[1], acc, 0, 0, 0);
        acc = __builtin_amdgcn_mfma_f32_16x16x32_bf16(al[rt][0], bh[0], acc, 0, 0, 0);
        acc = __builtin_amdgcn_mfma_f32_16x16x32_bf16(al[rt][1], bh[1], acc, 0, 0, 0);
        acc = __builtin_amdgcn_mfma_f32_16x16x32_bf16(ah[rt][0], bl[0], acc, 0, 0, 0);
        acc = __builtin_amdgcn_mfma_f32_16x16x32_bf16(ah[rt][1], bl[1], acc, 0, 0, 0);
#pragma unroll
        for (int j = 0; j < 4; ++j) {
          float s = fmaf(-2.f, acc[j], cnv);                 // > 0 by construction
          uint m = (__float_as_uint(s) & 0xFFFFFC00u) | kidx; // score | index packed
          int slot = rt * 4 + j;
          uint t = max(u1[slot], m);
          u1[slot] = min(u1[slot], m);
          u2[slot] = min(u2[slot], t);
        }
      }
    }
    if (c < 7) {
      stage_write((c + 1) & 1);
      if (c < 6) stage_load(c + 2);
    }
    __syncthreads();
  }

  // ---- cross-lane top-2 merge over the 16 code-lanes; write best ----
#pragma unroll
  for (int rt = 0; rt < 4; ++rt) {
#pragma unroll
    for (int j = 0; j < 4; ++j) {
      int slot = rt * 4 + j;
      uint a1 = u1[slot], a2 = u2[slot];
#pragma unroll
      for (int off = 1; off < 16; off <<= 1) {
        uint o1 = (uint)__shfl_xor((int)a1, off);
        uint o2 = (uint)__shfl_xor((int)a2, off);
        a2 = min(min(a2, o2), max(a1, o1));
        a1 = min(a1, o1);
      }
      if (l15 == 0) {
        uint k = a1 & 1023u;
        float f1 = __uint_as_float(a1 & 0xFFFFFC00u);
        float f2 = __uint_as_float(a2 & 0xFFFFFC00u);
        ushort v = (ushort)k;
        if (f2 - f1 < EPS_FLAG) v |= 0x8000;               // near-tie: exact recheck
        best[brow + wrow + rt * 16 + lg * 4 + j] = v;
      }
    }
  }
}

// ---------------- cleanup: exact fp32 recheck of flagged rows + counts histogram ----------------
__global__ __launch_bounds__(256)
void nsvq_cleanup(const float* __restrict__ x,
                  const float* __restrict__ cb,
                  const float* __restrict__ cn,
                  ushort* __restrict__ best,
                  int* __restrict__ counts, int N, int K) {
  __shared__ int hist[1024];
  for (int i = threadIdx.x; i < K; i += 256) hist[i] = 0;
  __syncthreads();
  const int lane = threadIdx.x & 63;
  const int wave = (blockIdx.x << 2) | (threadIdx.x >> 6);
  const long r0 = (long)wave * 64;
  for (long row = r0; row < r0 + 64; ++row) {
    ushort b = best[row];
    if (!(b & 0x8000)) {
      if (lane == 0) atomicAdd(&hist[b & 0x3FF], 1);
      continue;
    }
    // exact fp32 rescan over all K codes: lane handles codes [lane*16, lane*16+16)
    float4 xr[16];
#pragma unroll
    for (int q = 0; q < 16; ++q) xr[q] = *(const float4*)(x + row * NSVQ_D + q * 4);
    float bs = 3.4e38f;
    int bk = 0;
    for (int m = 0; m < 16; ++m) {
      int k = lane * 16 + m;
      const float4* cp = (const float4*)(cb + (long)k * NSVQ_D);
      float dot = 0.f;
#pragma unroll
      for (int q = 0; q < 16; ++q) {
        float4 cv = cp[q];
        dot = fmaf(xr[q].x, cv.x, dot);
        dot = fmaf(xr[q].y, cv.y, dot);
        dot = fmaf(xr[q].z, cv.z, dot);
        dot = fmaf(xr[q].w, cv.w, dot);
      }
      float s = fmaf(-2.f, dot, cn[k]);   // cn includes +256: uniform shift, argmin-safe
      if (s < bs) { bs = s; bk = k; }
    }
#pragma unroll
    for (int off = 1; off < 64; off <<= 1) {
      float s2v = __shfl_xor(bs, off);
      int k2 = __shfl_xor(bk, off);
      if (s2v < bs || (s2v == bs && k2 < bk)) { bs = s2v; bk = k2; }
    }
    if (lane == 0) {
      best[row] = (ushort)bk;
      atomicAdd(&hist[bk], 1);
    }
  }
  __syncthreads();
  for (int i = threadIdx.x; i < K; i += 256) {
    int v = hist[i];
    if (v) atomicAdd(&counts[i], v);
  }
}

// ---------------- epilogue: noise-substitution quantization ----------------
__global__ __launch_bounds__(256)
void nsvq_epilogue_kernel(const float* __restrict__ x,
                          const float* __restrict__ cb,
                          const float* __restrict__ rv,
                          const ushort* __restrict__ best,
                          float* __restrict__ out) {
  const int tid = threadIdx.x;
  const long row = (long)blockIdx.x * 16 + (tid >> 4);
  const int l = tid & 15;
  const int k = best[row] & 0x3FF;

  float4 xv = ((const float4*)(x + row * NSVQ_D))[l];
  float4 cv = ((const float4*)(cb + (long)k * NSVQ_D))[l];
  float4 rr = ((const float4*)(rv + row * NSVQ_D))[l];

  float dx = xv.x - cv.x, dy = xv.y - cv.y, dz = xv.z - cv.z, dw = xv.w - cv.w;
  float dres = dx * dx + dy * dy + dz * dz + dw * dw;
  float drnd = rr.x * rr.x + rr.y * rr.y + rr.z * rr.z + rr.w * rr.w;
#pragma unroll
  for (int off = 1; off < 16; off <<= 1) {
    dres += __shfl_xor(dres, off, 64);
    drnd += __shfl_xor(drnd, off, 64);
  }
  float scale = sqrtf(dres) / (sqrtf(drnd) + 1e-12f);

  float4 o;
  o.x = xv.x + scale * rr.x;
  o.y = xv.y + scale * rr.y;
  o.z = xv.z + scale * rr.z;
  o.w = xv.w + scale * rr.w;
  ((float4*)(out + row * NSVQ_D))[l] = o;
}

// ---------------- perplexity + counts output ----------------
__global__ void nsvq_perp_kernel(const int* __restrict__ counts,
                                 float* __restrict__ out_tail,  // [0]=perp, [1..K]=counts
                                 float invN, int K) {
  int t = threadIdx.x;
  float v = 0.f;
  if (t < K) {
    int c = counts[t];
    out_tail[1 + t] = (float)c;
    float p = (float)c * invN;
    v = p * logf(p + 1e-12f);
  }
#pragma unroll
  for (int off = 1; off < 64; off <<= 1) v += __shfl_xor(v, off, 64);
  __shared__ float red[16];
  int wid = t >> 6;
  if ((t & 63) == 0) red[wid] = v;
  __syncthreads();
  if (t == 0) {
    float s = 0.f;
    int nw = (blockDim.x + 63) / 64;
    for (int w = 0; w < nw; ++w) s += red[w];
    out_tail[0] = expf(-s);
  }
}

extern "C" void kernel_launch(void* const* d_in, const int* in_sizes, int n_in,
                              void* d_out, int out_size, void* d_ws, size_t ws_size,
                              hipStream_t stream) {
  const float* x  = (const float*)d_in[0];
  const float* cb = (const float*)d_in[1];
  const float* rv = (const float*)d_in[2];
  float* out = (float*)d_out;

  const int D = NSVQ_D;
  const int N = in_sizes[0] / D;  // 131072
  const int K = in_sizes[1] / D;  // 1024

  float*  cn     = (float*)d_ws;
  int*    counts = (int*)((char*)d_ws + 4096);
  ushort* best   = (ushort*)((char*)d_ws + 8192);
  ushort* cbh    = (ushort*)((char*)d_ws + 270336);
  ushort* cbl    = (ushort*)((char*)d_ws + 401408);

  nsvq_prep<<<(K + 255) / 256, 256, 0, stream>>>(cb, cbh, cbl, cn, counts, K);
  nsvq_argmin_mfma<<<N / ABN, 512, 0, stream>>>(x, cbh, cbl, cn, best);
  nsvq_cleanup<<<N / (64 * 4), 256, 0, stream>>>(x, cb, cn, best, counts, N, K);
  nsvq_epilogue_kernel<<<N / 16, 256, 0, stream>>>(x, cb, rv, best, out);
  nsvq_perp_kernel<<<1, 1024, 0, stream>>>(counts, out + (size_t)N * D, 1.0f / (float)N, K);
}

// Round 5
// 108.179 us; speedup vs baseline: 2.9831x; 2.8022x over previous
//
#include <hip/hip_runtime.h>
#include <math.h>

// NSVQ: N=131072 rows, D=64, K=1024 codes (fp32).
// out (flat f32): [0,N*D) quantized; [N*D] perplexity; [N*D+1,+K) counts.
// ws layout:
//   [0,4096)         cn4k   f32[K]     4096*(||c||^2 + 512)
//   [4096,8192)      counts int[K]
//   [8192,532480)    best   uint[N]    bit31=flag, bits10..19=k2, bits0..9=k1
//   [532480,663552)  cbh    ushort[K*64] bf16 hi, swizzled 16B blocks
//   [663552,794624)  cbl    ushort[K*64] bf16 lo, swizzled 16B blocks

#define NSVQ_D 64
#define ABN 512      // rows per argmin block
#define THR_Q 100u   // flag threshold in 1/4096 score quanta (~0.024)

typedef __attribute__((ext_vector_type(8))) short short8;
typedef __attribute__((ext_vector_type(4))) float f32x4;

__device__ __forceinline__ ushort bftrunc(float f) {
  return (ushort)(__float_as_uint(f) >> 16);
}
__device__ __forceinline__ float bf2f(ushort h) {
  return __uint_as_float(((uint)h) << 16);
}

// ---------------- prep: codebook norms + bf16 hi/lo split (swizzled) + zero counts ----------------
__global__ __launch_bounds__(256)
void nsvq_prep(const float* __restrict__ cb,
               ushort* __restrict__ cbh, ushort* __restrict__ cbl,
               float* __restrict__ cn4k, int* __restrict__ counts, int K) {
  if (blockIdx.x == 0) ((int4*)counts)[threadIdx.x] = make_int4(0, 0, 0, 0);
  int r = blockIdx.x * 256 + threadIdx.x;  // one code per thread
  if (r >= K) return;
  const float* row = cb + (long)r * NSVQ_D;
  float nrm = 0.f;
#pragma unroll
  for (int j = 0; j < 8; ++j) {            // dim block j = dims 8j..8j+7
    float4 v0 = *(const float4*)(row + j * 8);
    float4 v1 = *(const float4*)(row + j * 8 + 4);
    float f[8] = {v0.x, v0.y, v0.z, v0.w, v1.x, v1.y, v1.z, v1.w};
    ushort h[8], l[8];
#pragma unroll
    for (int e = 0; e < 8; ++e) {
      nrm = fmaf(f[e], f[e], nrm);
      ushort hb = bftrunc(f[e]);
      h[e] = hb;
      l[e] = bftrunc(f[e] - bf2f(hb));
    }
    int blk = r * 8 + (j ^ (r & 7));       // swizzled 16B block index
    *(uint4*)(cbh + blk * 8) = *(uint4*)h;
    *(uint4*)(cbl + blk * 8) = *(uint4*)l;
  }
  cn4k[r] = 4096.f * (nrm + 512.f);        // offset keeps scores in (0, 1024)
}

// ---------------- MFMA argmin: 512 rows/block, fixed-point packed top-2 ----------------
__global__ __launch_bounds__(512, 2)
void nsvq_argmin_mfma(const float* __restrict__ x,
                      const ushort* __restrict__ cbh,
                      const ushort* __restrict__ cbl,
                      const float* __restrict__ cn4k,
                      uint* __restrict__ best) {
  __shared__ ushort CS[2][2][128 * 64];    // [buf][hi/lo][code*64], 64 KB, swizzled
  const int tid = threadIdx.x;
  const int lane = tid & 63;
  const int wid = tid >> 6;                // 0..7, each wave owns 64 rows
  const int l15 = lane & 15;
  const int lg = lane >> 4;                // 0..3
  const long brow = (long)blockIdx.x * ABN;
  const int wrow = wid * 64;

  // ---- A fragments (X rows scaled by 4096), bf16 hi/lo, register-resident ----
  short8 ah[4][2], al[4][2];
#pragma unroll
  for (int rt = 0; rt < 4; ++rt) {
#pragma unroll
    for (int kk = 0; kk < 2; ++kk) {
      const float* xr = x + (brow + wrow + rt * 16 + l15) * NSVQ_D + kk * 32 + lg * 8;
      float4 v0 = *(const float4*)xr;
      float4 v1 = *(const float4*)(xr + 4);
      float f[8] = {v0.x, v0.y, v0.z, v0.w, v1.x, v1.y, v1.z, v1.w};
      short8 h, lo;
#pragma unroll
      for (int j = 0; j < 8; ++j) {
        float fs = f[j] * 4096.f;          // exact power-of-2 scale
        ushort hb = bftrunc(fs);
        h[j] = (short)hb;
        lo[j] = (short)bftrunc(fs - bf2f(hb));
      }
      ah[rt][kk] = h;
      al[rt][kk] = lo;
    }
  }

  // ---- linear chunk staging (pre-swizzled in ws): 32 KB per chunk ----
  uint4 st[4];
  auto stage_load = [&](int c) {
    const uint4* ph = (const uint4*)cbh + c * 1024;
    const uint4* pl = (const uint4*)cbl + c * 1024;
    st[0] = ph[tid];
    st[1] = ph[tid + 512];
    st[2] = pl[tid];
    st[3] = pl[tid + 512];
  };
  auto stage_write = [&](int b) {
    uint4* dh = (uint4*)&CS[b][0][0];
    uint4* dl = (uint4*)&CS[b][1][0];
    dh[tid] = st[0];
    dh[tid + 512] = st[1];
    dl[tid] = st[2];
    dl[tid + 512] = st[3];
  };

  uint u1[16], u2[16];
#pragma unroll
  for (int i = 0; i < 16; ++i) { u1[i] = 0xFFFFFFFFu; u2[i] = 0xFFFFFFFFu; }

  stage_load(0);
  stage_write(0);
  stage_load(1);
  __syncthreads();

  for (int c = 0; c < 8; ++c) {            // 8 chunks x 128 codes
    char* chb = (char*)&CS[c & 1][0][0];
    char* clb = (char*)&CS[c & 1][1][0];
#pragma unroll
    for (int ct = 0; ct < 8; ++ct) {
      int crow = ct * 16 + l15;            // code within chunk
      short8 bh[2], bl[2];
#pragma unroll
      for (int kk = 0; kk < 2; ++kk) {
        int byteoff = crow * 128 + ((((kk << 2) + lg) ^ (crow & 7)) << 4);
        bh[kk] = *(short8*)(chb + byteoff);
        bl[kk] = *(short8*)(clb + byteoff);
      }
      uint kidx = (uint)(c * 128 + crow);
      float cnv = cn4k[kidx];
#pragma unroll
      for (int rt = 0; rt < 4; ++rt) {
        f32x4 acc = {0.f, 0.f, 0.f, 0.f};
        acc = __builtin_amdgcn_mfma_f32_16x16x32_bf16(ah[rt][0], bh[0], acc, 0, 0, 0);
        acc = __builtin_amdgcn_mfma_f32_16x16x32_bf16(ah[rt][1], bh[1], acc, 0, 0, 0);
        acc = __builtin_amdgcn_mfma_f32_16x16x32_bf16(al[rt][0], bh[0], acc, 0, 0, 0);
        acc = __builtin_amdgcn_mfma_f32_16x16x32_bf16(al[rt][1], bh[1], acc, 0, 0, 0);
        acc = __builtin_amdgcn_mfma_f32_16x16x32_bf16(ah[rt][0], bl[0], acc, 0, 0, 0);
        acc = __builtin_amdgcn_mfma_f32_16x16x32_bf16(ah[rt][1], bl[1], acc, 0, 0, 0);
#pragma unroll
        for (int j = 0; j < 4; ++j) {
          float s = fmaf(-2.f, acc[j], cnv);        // 4096*score, in (0, 2^22)
          uint m = ((uint)s << 10) | kidx;          // fixed-point | index
          int slot = rt * 4 + j;
          uint t = max(u1[slot], m);
          u1[slot] = min(u1[slot], m);
          u2[slot] = min(u2[slot], t);
        }
      }
    }
    if (c < 7) {
      stage_write((c + 1) & 1);
      if (c < 6) stage_load(c + 2);
    }
    __syncthreads();
  }

  // ---- cross-lane top-2 merge over the 16 code-lanes; write packed best ----
#pragma unroll
  for (int rt = 0; rt < 4; ++rt) {
#pragma unroll
    for (int j = 0; j < 4; ++j) {
      int slot = rt * 4 + j;
      uint a1 = u1[slot], a2 = u2[slot];
#pragma unroll
      for (int off = 1; off < 16; off <<= 1) {
        uint o1 = (uint)__shfl_xor((int)a1, off);
        uint o2 = (uint)__shfl_xor((int)a2, off);
        a2 = min(min(a2, o2), max(a1, o1));
        a1 = min(a1, o1);
      }
      if (l15 == 0) {
        uint fl = ((a2 >> 10) - (a1 >> 10) < THR_Q) ? 0x80000000u : 0u;
        best[brow + wrow + rt * 16 + lg * 4 + j] =
            fl | ((a2 & 1023u) << 10) | (a1 & 1023u);
      }
    }
  }
}

// ---------------- cleanup: per-thread top-2 exact check + counts histogram ----------------
__global__ __launch_bounds__(256)
void nsvq_cleanup(const float* __restrict__ x,
                  const float* __restrict__ cb,
                  const float* __restrict__ cn4k,
                  uint* __restrict__ best,
                  int* __restrict__ counts) {
  __shared__ int hist[1024];
#pragma unroll
  for (int i = threadIdx.x; i < 1024; i += 256) hist[i] = 0;
  __syncthreads();

  const long row = (long)blockIdx.x * 256 + threadIdx.x;
  uint p = best[row];
  uint k = p & 1023u;
  if (p & 0x80000000u) {
    uint k2 = (p >> 10) & 1023u;
    const float4* xr = (const float4*)(x + row * NSVQ_D);
    const float4* c1 = (const float4*)(cb + (long)k * NSVQ_D);
    const float4* c2 = (const float4*)(cb + (long)k2 * NSVQ_D);
    float d1 = 0.f, d2 = 0.f;
#pragma unroll
    for (int q = 0; q < 16; ++q) {
      float4 xv = xr[q], a = c1[q], b = c2[q];
      d1 = fmaf(xv.x, a.x, d1); d1 = fmaf(xv.y, a.y, d1);
      d1 = fmaf(xv.z, a.z, d1); d1 = fmaf(xv.w, a.w, d1);
      d2 = fmaf(xv.x, b.x, d2); d2 = fmaf(xv.y, b.y, d2);
      d2 = fmaf(xv.z, b.z, d2); d2 = fmaf(xv.w, b.w, d2);
    }
    float s1 = fmaf(-8192.f, d1, cn4k[k]);   // 4096*score, exact fp32 dot
    float s2 = fmaf(-8192.f, d2, cn4k[k2]);
    if (s2 < s1 || (s2 == s1 && k2 < k)) k = k2;
    best[row] = k;                            // clean entry for epilogue
  }
  atomicAdd(&hist[k], 1);
  __syncthreads();
  for (int i = threadIdx.x; i < 1024; i += 256) {
    int v = hist[i];
    if (v) atomicAdd(&counts[i], v);
  }
}

// ---------------- epilogue: noise-substitution quantization ----------------
__global__ __launch_bounds__(256)
void nsvq_epilogue_kernel(const float* __restrict__ x,
                          const float* __restrict__ cb,
                          const float* __restrict__ rv,
                          const uint* __restrict__ best,
                          float* __restrict__ out) {
  const int tid = threadIdx.x;
  const long row = (long)blockIdx.x * 16 + (tid >> 4);
  const int l = tid & 15;
  const int k = (int)(best[row] & 1023u);

  float4 xv = ((const float4*)(x + row * NSVQ_D))[l];
  float4 cv = ((const float4*)(cb + (long)k * NSVQ_D))[l];
  float4 rr = ((const float4*)(rv + row * NSVQ_D))[l];

  float dx = xv.x - cv.x, dy = xv.y - cv.y, dz = xv.z - cv.z, dw = xv.w - cv.w;
  float dres = dx * dx + dy * dy + dz * dz + dw * dw;
  float drnd = rr.x * rr.x + rr.y * rr.y + rr.z * rr.z + rr.w * rr.w;
#pragma unroll
  for (int off = 1; off < 16; off <<= 1) {
    dres += __shfl_xor(dres, off, 64);
    drnd += __shfl_xor(drnd, off, 64);
  }
  float scale = sqrtf(dres) / (sqrtf(drnd) + 1e-12f);

  float4 o;
  o.x = xv.x + scale * rr.x;
  o.y = xv.y + scale * rr.y;
  o.z = xv.z + scale * rr.z;
  o.w = xv.w + scale * rr.w;
  ((float4*)(out + row * NSVQ_D))[l] = o;
}

// ---------------- perplexity + counts output ----------------
__global__ void nsvq_perp_kernel(const int* __restrict__ counts,
                                 float* __restrict__ out_tail,  // [0]=perp, [1..K]=counts
                                 float invN, int K) {
  int t = threadIdx.x;
  float v = 0.f;
  if (t < K) {
    int c = counts[t];
    out_tail[1 + t] = (float)c;
    float p = (float)c * invN;
    v = p * logf(p + 1e-12f);
  }
#pragma unroll
  for (int off = 1; off < 64; off <<= 1) v += __shfl_xor(v, off, 64);
  __shared__ float red[16];
  int wid = t >> 6;
  if ((t & 63) == 0) red[wid] = v;
  __syncthreads();
  if (t == 0) {
    float s = 0.f;
    int nw = (blockDim.x + 63) / 64;
    for (int w = 0; w < nw; ++w) s += red[w];
    out_tail[0] = expf(-s);
  }
}

extern "C" void kernel_launch(void* const* d_in, const int* in_sizes, int n_in,
                              void* d_out, int out_size, void* d_ws, size_t ws_size,
                              hipStream_t stream) {
  const float* x  = (const float*)d_in[0];
  const float* cb = (const float*)d_in[1];
  const float* rv = (const float*)d_in[2];
  float* out = (float*)d_out;

  const int D = NSVQ_D;
  const int N = in_sizes[0] / D;  // 131072
  const int K = in_sizes[1] / D;  // 1024

  float*  cn4k   = (float*)d_ws;
  int*    counts = (int*)((char*)d_ws + 4096);
  uint*   best   = (uint*)((char*)d_ws + 8192);
  ushort* cbh    = (ushort*)((char*)d_ws + 532480);
  ushort* cbl    = (ushort*)((char*)d_ws + 663552);

  nsvq_prep<<<(K + 255) / 256, 256, 0, stream>>>(cb, cbh, cbl, cn4k, counts, K);
  nsvq_argmin_mfma<<<N / ABN, 512, 0, stream>>>(x, cbh, cbl, cn4k, best);
  nsvq_cleanup<<<N / 256, 256, 0, stream>>>(x, cb, cn4k, best, counts);
  nsvq_epilogue_kernel<<<N / 16, 256, 0, stream>>>(x, cb, rv, best, out);
  nsvq_perp_kernel<<<1, 1024, 0, stream>>>(counts, out + (size_t)N * D, 1.0f / (float)N, K);
}